// Round 3
// baseline (105.668 us; speedup 1.0000x reference)
//
#include <hip/hip_runtime.h>
#include <hip/hip_bf16.h>
#include <hip/hip_cooperative_groups.h>
#include <math.h>

namespace cg = cooperative_groups;

// B=4, N=512, T=288, L=128
#define NB 4
#define NN 512
#define NT 288
#define NL 128

// ---------------------------------------------------------------------------
// Megakernel: 256 blocks x 512 threads, cooperative, grid.sync between phases.
// Phase A: x -> x1,x2 (leaky) -> S1|S2 (=S12) + per-row dots A[bn], C[bn].
// Phase B: pairwise acc(i,j) = sum_l |S1[i][l]+S2[j][l]|*Wb[l] -> sigmoid -> PS4.
// Phase F: p = mean_b sigmoid ; zero diag ; logit clamp ; noise logistic ; out.
// LDS: one 66 KB union.
//   A: xs[2304] (aliased s12s[8][257]) | x12s[2048] | ph[2048]
//   B: S1t[8192] | S2t[8192] | wbs[128]
// ---------------------------------------------------------------------------
__global__ __launch_bounds__(512) void mega(
    const float* __restrict__ x,   // [2048][288]
    const float* __restrict__ W1,  // [128][288]
    const float* __restrict__ b1,  // [128]
    const float* __restrict__ W2,  // [128][288]
    const float* __restrict__ b2,  // [128]
    const float* __restrict__ Wp,  // [128][256]
    const float* __restrict__ bp,  // [128]
    const float* __restrict__ Wb,  // [128]
    const float* __restrict__ bb,  // [1]
    const float* __restrict__ noise, // [512][512]
    float* __restrict__ S12,       // ws [2048][256]
    float* __restrict__ Aarr,      // ws [2048]
    float* __restrict__ Carr,      // ws [2048]
    float* __restrict__ PS4,       // ws [4][512][512]
    float* __restrict__ out)       // [512][512]
{
    __shared__ __align__(16) float smem[16512];   // 66048 B
    cg::grid_group grid = cg::this_grid();

    const int t = threadIdx.x;

    // ===================== Phase A =====================
    {
        float* xs   = smem;          // 8*288 = 2304 (alias s12s[8][257] = 2056)
        float* x12s = smem + 2304;   // 8*256
        float* ph   = smem + 4352;   // 8*256

        const int bn0 = blockIdx.x * 8;
        const int col = t & 255;
        const int kh = t >> 8;       // K-half

        // stage 8 x-rows (576 float4)
        for (int q = 0; q < 2; ++q) {
            int idx = q * 512 + t;
            if (idx < 576) {
                int row = idx / 72, c4 = idx % 72;
                *(float4*)&xs[row * NT + c4 * 4] =
                    *(const float4*)&x[(size_t)(bn0 + row) * NT + c4 * 4];
            }
        }
        __syncthreads();

        // G1: col of [x1|x2] for 8 rows; K=288 split 144/144
        const float* wrow = ((col < 128) ? (W1 + col * NT) : (W2 + (col - 128) * NT))
                            + kh * 144;
        const float bias1 = (col < 128) ? b1[col] : b2[col - 128];
        const int kb1 = kh * 144;

        float acc[8];
#pragma unroll
        for (int n = 0; n < 8; ++n) acc[n] = 0.0f;

        for (int k = 0; k < 144; k += 4) {
            float4 w = *(const float4*)(wrow + k);
#pragma unroll
            for (int n = 0; n < 8; ++n) {
                float4 xv = *(const float4*)&xs[n * NT + kb1 + k];
                acc[n] = fmaf(w.x, xv.x, acc[n]);
                acc[n] = fmaf(w.y, xv.y, acc[n]);
                acc[n] = fmaf(w.z, xv.z, acc[n]);
                acc[n] = fmaf(w.w, xv.w, acc[n]);
            }
        }
        if (kh) {
#pragma unroll
            for (int n = 0; n < 8; ++n) ph[n * 256 + col] = acc[n];
        }
        __syncthreads();
        if (!kh) {
#pragma unroll
            for (int n = 0; n < 8; ++n) {
                float v = acc[n] + ph[n * 256 + col] + bias1;
                x12s[n * 256 + col] = fmaxf(v, 0.2f * v);   // leaky
            }
        }
        __syncthreads();

        // G2: col of [S1|S2] for 8 rows; K=128 split 64/64
        const int koff = (col < 128) ? 0 : 128;
        const float* wprow = ((col < 128) ? (Wp + col * 256) : (Wp + (col - 128) * 256 + 128))
                             + kh * 64;
        const float bias2 = (col < 128) ? bp[col] : 0.0f;
        const int kb2 = koff + kh * 64;

        float acc2[8];
#pragma unroll
        for (int n = 0; n < 8; ++n) acc2[n] = 0.0f;

        for (int k = 0; k < 64; k += 4) {
            float4 w = *(const float4*)(wprow + k);
#pragma unroll
            for (int n = 0; n < 8; ++n) {
                float4 xv = *(const float4*)&x12s[n * 256 + kb2 + k];
                acc2[n] = fmaf(w.x, xv.x, acc2[n]);
                acc2[n] = fmaf(w.y, xv.y, acc2[n]);
                acc2[n] = fmaf(w.z, xv.z, acc2[n]);
                acc2[n] = fmaf(w.w, xv.w, acc2[n]);
            }
        }
        if (kh) {
#pragma unroll
            for (int n = 0; n < 8; ++n) ph[n * 256 + col] = acc2[n];
        }
        __syncthreads();

        float* s12s = xs;   // alias: xs dead after G1
        if (!kh) {
#pragma unroll
            for (int n = 0; n < 8; ++n) {
                float sv = acc2[n] + ph[n * 256 + col] + bias2;
                S12[(size_t)(bn0 + n) * 256 + col] = sv;
                s12s[n * 257 + col] = sv;
            }
        }
        __syncthreads();

        // per-row dots with Wb: 16 dots x 32 lanes
        {
            int lane32 = t & 31;
            int n = (t >> 5) & 7;
            int isC = t >> 8;
            int base = isC ? 128 : 0;
            float sum = 0.0f;
#pragma unroll
            for (int s = 0; s < 4; ++s) {
                int j = lane32 + s * 32;
                sum = fmaf(s12s[n * 257 + base + j], Wb[j], sum);
            }
#pragma unroll
            for (int m = 16; m >= 1; m >>= 1)
                sum += __shfl_xor(sum, m, 32);
            if (lane32 == 0) {
                if (isC) Carr[bn0 + n] = 0.6f * sum;
                else     Aarr[bn0 + n] = 0.6f * sum + bb[0];
            }
        }
    }

    grid.sync();

    // ===================== Phase B =====================
    {
        float* S1t = smem;           // 128*64
        float* S2t = smem + 8192;    // 128*64
        float* wbs = smem + 16384;   // 128

        const int bx = blockIdx.x & 7;
        const int by = (blockIdx.x >> 3) & 7;
        const int bz = blockIdx.x >> 6;
        const int ibn0 = bz * NN + bx * 64;
        const int jbn0 = bz * NN + by * 64;

        if (t < 32) *(float4*)&wbs[t * 4] = *(const float4*)&Wb[t * 4];

        // stage both tiles (64 rows x 128 cols), transposed + XOR swizzle
#pragma unroll
        for (int q = 0; q < 4; ++q) {
            int idx = q * 512 + t;      // float4 index 0..2047
            int row = idx >> 5;         // 0..63
            int c4 = idx & 31;          // col = c4*4
            float4 v1 = *(const float4*)&S12[(size_t)(ibn0 + row) * 256 + c4 * 4];
            float4 v2 = *(const float4*)&S12[(size_t)(jbn0 + row) * 256 + 128 + c4 * 4];
            float a1[4] = {v1.x, v1.y, v1.z, v1.w};
            float a2[4] = {v2.x, v2.y, v2.z, v2.w};
#pragma unroll
            for (int d = 0; d < 4; ++d) {
                int l = c4 * 4 + d;
                int sw = ((l >> 2) & 15) << 2;
                S1t[l * 64 + (row ^ sw)] = a1[d];
                S2t[l * 64 + (row ^ sw)] = a2[d];
            }
        }
        __syncthreads();

        const int tid = t & 255;
        const int lh = t >> 8;                 // l-half
        const int tx = tid & 15, ty = tid >> 4;
        const int i0 = ty * 4, j0 = tx * 4;
        const int lbase = lh * 64;

        float accv[16];
#pragma unroll
        for (int k = 0; k < 16; ++k) accv[k] = 0.0f;

        for (int l4 = 0; l4 < 16; ++l4) {
            const int sw = l4 << 2;
            const int lrow = (lbase + l4 * 4) * 64;
            float4 wv = *(const float4*)&wbs[lbase + l4 * 4];
            const float wl[4] = {wv.x, wv.y, wv.z, wv.w};
#pragma unroll
            for (int d = 0; d < 4; ++d) {
                float4 a = *(const float4*)&S1t[lrow + d * 64 + (i0 ^ sw)];
                float4 b = *(const float4*)&S2t[lrow + d * 64 + (j0 ^ sw)];
                float w = wl[d];
                float ai[4] = {a.x, a.y, a.z, a.w};
                float bj[4] = {b.x, b.y, b.z, b.w};
#pragma unroll
                for (int ii = 0; ii < 4; ++ii)
#pragma unroll
                    for (int jj = 0; jj < 4; ++jj) {
                        float tv = ai[ii] + bj[jj];
                        accv[ii * 4 + jj] = fmaf(fabsf(tv), w, accv[ii * 4 + jj]);
                    }
            }
        }

        // cross-reduce the two l-halves through LDS (alias onto S1t)
        float* red = S1t;
        __syncthreads();
        if (lh) {
#pragma unroll
            for (int q = 0; q < 4; ++q) {
                float4 v = {accv[4 * q], accv[4 * q + 1], accv[4 * q + 2], accv[4 * q + 3]};
                *(float4*)&red[q * 1024 + tid * 4] = v;
            }
        }
        __syncthreads();
        if (!lh) {
#pragma unroll
            for (int q = 0; q < 4; ++q) {
                float4 v = *(const float4*)&red[q * 1024 + tid * 4];
                accv[4 * q]     += v.x;
                accv[4 * q + 1] += v.y;
                accv[4 * q + 2] += v.z;
                accv[4 * q + 3] += v.w;
            }

            float Av[4], Cv[4];
#pragma unroll
            for (int ii = 0; ii < 4; ++ii) Av[ii] = Aarr[ibn0 + i0 + ii];
#pragma unroll
            for (int jj = 0; jj < 4; ++jj) Cv[jj] = Carr[jbn0 + j0 + jj];

#pragma unroll
            for (int ii = 0; ii < 4; ++ii) {
                float4 o;
                float* op = (float*)&o;
#pragma unroll
                for (int jj = 0; jj < 4; ++jj) {
                    float lg = Av[ii] + Cv[jj] + 0.4f * accv[ii * 4 + jj];
                    op[jj] = 1.0f / (1.0f + expf(-lg));
                }
                *(float4*)&PS4[(size_t)bz * (NN * NN) +
                               (size_t)(bx * 64 + i0 + ii) * NN + by * 64 + j0] = o;
            }
        }
    }

    grid.sync();

    // ===================== Phase F =====================
    {
        int f = blockIdx.x * 1024 + t * 2;    // element index, 2 per thread
        int i = f >> 9;
        int jbase = f & 511;

        float2 s0 = *(const float2*)&PS4[f];
        float2 s1 = *(const float2*)&PS4[262144 + f];
        float2 s2 = *(const float2*)&PS4[524288 + f];
        float2 s3 = *(const float2*)&PS4[786432 + f];
        float2 nz = *(const float2*)&noise[f];

        float ps[2] = {s0.x + s1.x + s2.x + s3.x,
                       s0.y + s1.y + s2.y + s3.y};
        float nv[2] = {nz.x, nz.y};

        float2 o;
        float* op = (float*)&o;
#pragma unroll
        for (int c = 0; c < 2; ++c) {
            float p = 0.25f * ps[c];
            if (jbase + c == i) p = 0.0f;
            float lp = logf(p + 1e-10f) - log1pf(-p + 1e-10f);
            lp = fminf(fmaxf(lp, -10.0f), 10.0f);
            float lgs = logf(nv[c]) - log1pf(-nv[c]);
            op[c] = 1.0f / (1.0f + expf(-(lp + lgs) * 5.0f));
        }
        *(float2*)&out[f] = o;
    }
}

// ---------------------------------------------------------------------------
extern "C" void kernel_launch(void* const* d_in, const int* in_sizes, int n_in,
                              void* d_out, int out_size, void* d_ws, size_t ws_size,
                              hipStream_t stream) {
    const float* x     = (const float*)d_in[0];
    const float* W1    = (const float*)d_in[1];
    const float* b1    = (const float*)d_in[2];
    const float* W2    = (const float*)d_in[3];
    const float* b2    = (const float*)d_in[4];
    const float* Wp    = (const float*)d_in[5];
    const float* bp    = (const float*)d_in[6];
    const float* Wb    = (const float*)d_in[7];
    const float* bb    = (const float*)d_in[8];
    const float* noise = (const float*)d_in[9];

    float* ws   = (float*)d_ws;
    float* S12  = ws;                 // 524288 floats
    float* Aarr = ws + 524288;        // 2048
    float* Carr = Aarr + 2048;        // 2048
    float* PS4  = Carr + 2048;        // 1048576 floats
    float* out  = (float*)d_out;

    void* params[] = {
        (void*)&x, (void*)&W1, (void*)&b1, (void*)&W2, (void*)&b2,
        (void*)&Wp, (void*)&bp, (void*)&Wb, (void*)&bb, (void*)&noise,
        (void*)&S12, (void*)&Aarr, (void*)&Carr, (void*)&PS4, (void*)&out
    };
    hipLaunchCooperativeKernel((const void*)mega, dim3(256), dim3(512),
                               params, 0, stream);
}

// Round 4
// 80.377 us; speedup vs baseline: 1.3147x; 1.3147x over previous
//
#include <hip/hip_runtime.h>
#include <hip/hip_bf16.h>
#include <math.h>

// B=4, N=512, T=288, L=128
#define NN 512

// ---------------------------------------------------------------------------
// Kernel P (phase A): x -> x1,x2 (leaky) -> S12=[S1|S2] + row dots A,C.
// 256 blocks x 512 threads, 8 bn-rows per block, thread=(col 0..255, kh 0..1).
// W1/W2/Wp read through LDS chunks stored TRANSPOSED [k][col] with XOR
// swizzle (colq^k) -> coalesced global loads, conflict-free b32 LDS reads.
// x read directly from global with wave-uniform addresses (L1/sK cached).
// Also zeroes P accumulator and tile counters for kernel Q.
// ---------------------------------------------------------------------------
__global__ __launch_bounds__(512) void kP(
    const float* __restrict__ x,   // [2048][288]
    const float* __restrict__ W1,  // [128][288]
    const float* __restrict__ b1,  // [128]
    const float* __restrict__ W2,  // [128][288]
    const float* __restrict__ b2,  // [128]
    const float* __restrict__ Wp,  // [128][256]
    const float* __restrict__ bp,  // [128]
    const float* __restrict__ Wb,  // [128]
    const float* __restrict__ bb,  // [1]
    float* __restrict__ S12,       // ws [2048][256]
    float* __restrict__ Aarr,      // ws [2048]
    float* __restrict__ Carr,      // ws [2048]
    float* __restrict__ P,         // ws [512][512]  (zeroed here)
    int*   __restrict__ cnt)       // ws [64]        (zeroed here)
{
    __shared__ __align__(16) float Wt[2][16][256];  // 32 KB, [kh][k][(cq^k)*4+j]
    __shared__ __align__(16) float x12s[8 * 256];   // 8 KB
    __shared__ __align__(16) float ph[8 * 256];     // 8 KB
    __shared__ __align__(16) float s12s[8 * 257];   // 8.2 KB

    const int t   = threadIdx.x;
    const int bn0 = blockIdx.x * 8;
    const int col = t & 255;
    const int kh  = t >> 8;
    const int khu = __builtin_amdgcn_readfirstlane(kh);  // wave-uniform copy
    const int cq  = col >> 2, cj = col & 3;

    // zero P (2 floats/thread) and counters for kernel Q
    *(float2*)&P[(size_t)(blockIdx.x * 512 + t) * 2] = make_float2(0.f, 0.f);
    if (blockIdx.x == 0 && t < 64) cnt[t] = 0;

    // ---- G1: [x1|x2] col per thread, K=288 split 144/144 over kh ----
    float acc[8];
#pragma unroll
    for (int n = 0; n < 8; ++n) acc[n] = 0.0f;

    for (int c = 0; c < 9; ++c) {          // 9 chunks of 16 k per half
        // stage W chunk transposed+swizzled: 2048 tasks, 4 per thread
#pragma unroll
        for (int i = 0; i < 4; ++i) {
            int task = i * 512 + t;
            int kk   = task & 15;
            int cq_s = (task >> 4) & 63;
            int khs  = task >> 10;
            int kb   = khs * 144 + c * 16 + kk;
            float4 v;
#pragma unroll
            for (int j = 0; j < 4; ++j) {
                int r = cq_s * 4 + j;
                const float* wr = (r < 128) ? (W1 + (size_t)r * 288)
                                            : (W2 + (size_t)(r - 128) * 288);
                ((float*)&v)[j] = wr[kb];
            }
            *(float4*)&Wt[khs][kk][((cq_s ^ kk) & 63) * 4] = v;
        }
        __syncthreads();

        const int kb0 = khu * 144 + c * 16;
#pragma unroll
        for (int k4 = 0; k4 < 4; ++k4) {
            float w[4];
#pragma unroll
            for (int d = 0; d < 4; ++d) {
                int k = k4 * 4 + d;
                w[d] = Wt[kh][k][((cq ^ k) & 63) * 4 + cj];
            }
#pragma unroll
            for (int n = 0; n < 8; ++n) {
                float4 xv = *(const float4*)&x[(size_t)(bn0 + n) * 288 + kb0 + k4 * 4];
                acc[n] = fmaf(w[0], xv.x, acc[n]);
                acc[n] = fmaf(w[1], xv.y, acc[n]);
                acc[n] = fmaf(w[2], xv.z, acc[n]);
                acc[n] = fmaf(w[3], xv.w, acc[n]);
            }
        }
        __syncthreads();   // Wt reused next chunk
    }

    const float bias1 = (col < 128) ? b1[col] : b2[col - 128];
    if (kh) {
#pragma unroll
        for (int n = 0; n < 8; ++n) ph[n * 256 + col] = acc[n];
    }
    __syncthreads();
    if (!kh) {
#pragma unroll
        for (int n = 0; n < 8; ++n) {
            float v = acc[n] + ph[n * 256 + col] + bias1;
            x12s[n * 256 + col] = fmaxf(v, 0.2f * v);   // leaky
        }
    }
    __syncthreads();

    // ---- G2: [S1|S2] col per thread, logical K=128 split 64/64 over kh ----
    float acc2[8];
#pragma unroll
    for (int n = 0; n < 8; ++n) acc2[n] = 0.0f;

    for (int c = 0; c < 4; ++c) {          // 4 chunks of 16 k per half
#pragma unroll
        for (int i = 0; i < 4; ++i) {
            int task = i * 512 + t;
            int kk   = task & 15;
            int cq_s = (task >> 4) & 63;
            int khs  = task >> 10;
            int kb   = khs * 64 + c * 16 + kk;   // logical k 0..127
            float4 v;
#pragma unroll
            for (int j = 0; j < 4; ++j) {
                int r = cq_s * 4 + j;            // output col 0..255
                const float* src = (r < 128) ? (Wp + (size_t)r * 256 + kb)
                                             : (Wp + (size_t)(r - 128) * 256 + 128 + kb);
                ((float*)&v)[j] = *src;
            }
            *(float4*)&Wt[khs][kk][((cq_s ^ kk) & 63) * 4] = v;
        }
        __syncthreads();

        const int koff = (col < 128) ? 0 : 128;  // x-half feeding this col
        const int kb0  = koff + kh * 64 + c * 16;
#pragma unroll
        for (int k4 = 0; k4 < 4; ++k4) {
            float w[4];
#pragma unroll
            for (int d = 0; d < 4; ++d) {
                int k = k4 * 4 + d;
                w[d] = Wt[kh][k][((cq ^ k) & 63) * 4 + cj];
            }
#pragma unroll
            for (int n = 0; n < 8; ++n) {
                float4 xv = *(const float4*)&x12s[n * 256 + kb0 + k4 * 4];
                acc2[n] = fmaf(w[0], xv.x, acc2[n]);
                acc2[n] = fmaf(w[1], xv.y, acc2[n]);
                acc2[n] = fmaf(w[2], xv.z, acc2[n]);
                acc2[n] = fmaf(w[3], xv.w, acc2[n]);
            }
        }
        __syncthreads();
    }

    const float bias2 = (col < 128) ? bp[col] : 0.0f;
    if (kh) {
#pragma unroll
        for (int n = 0; n < 8; ++n) ph[n * 256 + col] = acc2[n];
    }
    __syncthreads();
    if (!kh) {
#pragma unroll
        for (int n = 0; n < 8; ++n) {
            float sv = acc2[n] + ph[n * 256 + col] + bias2;
            S12[(size_t)(bn0 + n) * 256 + col] = sv;
            s12s[n * 257 + col] = sv;
        }
    }
    __syncthreads();

    // ---- per-row dots with Wb: 16 dots x 32 lanes ----
    {
        int lane32 = t & 31;
        int n = (t >> 5) & 7;
        int isC = t >> 8;
        int base = isC ? 128 : 0;
        float sum = 0.0f;
#pragma unroll
        for (int s = 0; s < 4; ++s) {
            int j = lane32 + s * 32;
            sum = fmaf(s12s[n * 257 + base + j], Wb[j], sum);
        }
#pragma unroll
        for (int m = 16; m >= 1; m >>= 1)
            sum += __shfl_xor(sum, m, 32);
        if (lane32 == 0) {
            if (isC) Carr[bn0 + n] = 0.6f * sum;
            else     Aarr[bn0 + n] = 0.6f * sum + bb[0];
        }
    }
}

// ---------------------------------------------------------------------------
// Kernel Q (phase B + fused F): grid (8,8,4), 512 threads.
// 64x64 tile, 4x4 per low-thread; l-range split 64/64 across thread halves.
// sigmoid(logits) accumulated into P via fp32 atomicAdd (device-scope);
// per-(bx,by) counter: 4th arriver reads P tile and does phase F -> out.
// ---------------------------------------------------------------------------
__global__ __launch_bounds__(512) void kQ(
    const float* __restrict__ S12,   // [2048][256]
    const float* __restrict__ Aarr,  // [2048]
    const float* __restrict__ Carr,  // [2048]
    const float* __restrict__ Wb,    // [128]
    const float* __restrict__ noise, // [512][512]
    float* __restrict__ P,           // ws [512][512] accumulator (pre-zeroed)
    int*   __restrict__ cnt,         // ws [64] (pre-zeroed)
    float* __restrict__ out)         // [512][512]
{
    __shared__ __align__(16) float S1t[128 * 64];
    __shared__ __align__(16) float S2t[128 * 64];
    __shared__ __align__(16) float wbs[128];
    __shared__ int lastf;

    const int t = threadIdx.x;
    const int bx = blockIdx.x, by = blockIdx.y, bz = blockIdx.z;
    const int ibn0 = bz * NN + bx * 64;
    const int jbn0 = bz * NN + by * 64;

    if (t < 32) *(float4*)&wbs[t * 4] = *(const float4*)&Wb[t * 4];

    // stage both tiles (64 rows x 128 cols), transposed + XOR swizzle
#pragma unroll
    for (int q = 0; q < 4; ++q) {
        int idx = q * 512 + t;      // float4 index 0..2047
        int row = idx >> 5;         // 0..63
        int c4 = idx & 31;          // col = c4*4
        float4 v1 = *(const float4*)&S12[(size_t)(ibn0 + row) * 256 + c4 * 4];
        float4 v2 = *(const float4*)&S12[(size_t)(jbn0 + row) * 256 + 128 + c4 * 4];
        float a1[4] = {v1.x, v1.y, v1.z, v1.w};
        float a2[4] = {v2.x, v2.y, v2.z, v2.w};
#pragma unroll
        for (int d = 0; d < 4; ++d) {
            int l = c4 * 4 + d;
            int sw = ((l >> 2) & 15) << 2;
            S1t[l * 64 + (row ^ sw)] = a1[d];
            S2t[l * 64 + (row ^ sw)] = a2[d];
        }
    }
    __syncthreads();

    const int tid = t & 255;
    const int lh = t >> 8;                 // l-half
    const int tx = tid & 15, ty = tid >> 4;
    const int i0 = ty * 4, j0 = tx * 4;
    const int lbase = lh * 64;

    float accv[16];
#pragma unroll
    for (int k = 0; k < 16; ++k) accv[k] = 0.0f;

    for (int l4 = 0; l4 < 16; ++l4) {
        const int sw = l4 << 2;
        const int lrow = (lbase + l4 * 4) * 64;
        float4 wv = *(const float4*)&wbs[lbase + l4 * 4];
        const float wl[4] = {wv.x, wv.y, wv.z, wv.w};
#pragma unroll
        for (int d = 0; d < 4; ++d) {
            float4 a = *(const float4*)&S1t[lrow + d * 64 + (i0 ^ sw)];
            float4 b = *(const float4*)&S2t[lrow + d * 64 + (j0 ^ sw)];
            float w = wl[d];
            float ai[4] = {a.x, a.y, a.z, a.w};
            float bj[4] = {b.x, b.y, b.z, b.w};
#pragma unroll
            for (int ii = 0; ii < 4; ++ii)
#pragma unroll
                for (int jj = 0; jj < 4; ++jj) {
                    float tv = ai[ii] + bj[jj];
                    accv[ii * 4 + jj] = fmaf(fabsf(tv), w, accv[ii * 4 + jj]);
                }
        }
    }

    // cross-reduce the two l-halves through LDS (alias onto S1t)
    float* red = S1t;
    __syncthreads();
    if (lh) {
#pragma unroll
        for (int q = 0; q < 4; ++q) {
            float4 v = {accv[4 * q], accv[4 * q + 1], accv[4 * q + 2], accv[4 * q + 3]};
            *(float4*)&red[q * 1024 + tid * 4] = v;
        }
    }
    __syncthreads();
    if (!lh) {
#pragma unroll
        for (int q = 0; q < 4; ++q) {
            float4 v = *(const float4*)&red[q * 1024 + tid * 4];
            accv[4 * q]     += v.x;
            accv[4 * q + 1] += v.y;
            accv[4 * q + 2] += v.z;
            accv[4 * q + 3] += v.w;
        }

        float Av[4], Cv[4];
#pragma unroll
        for (int ii = 0; ii < 4; ++ii) Av[ii] = Aarr[ibn0 + i0 + ii];
#pragma unroll
        for (int jj = 0; jj < 4; ++jj) Cv[jj] = Carr[jbn0 + j0 + jj];

#pragma unroll
        for (int ii = 0; ii < 4; ++ii)
#pragma unroll
            for (int jj = 0; jj < 4; ++jj) {
                float lg = Av[ii] + Cv[jj] + 0.4f * accv[ii * 4 + jj];
                float sig = 1.0f / (1.0f + expf(-lg));
                atomicAdd(&P[(size_t)(bx * 64 + i0 + ii) * NN + by * 64 + j0 + jj], sig);
            }
    }

    // ---- last-arriver does phase F for this (bx,by) tile ----
    __syncthreads();          // implies vmcnt drain: all atomics issued+done
    if (t == 0) {
        __threadfence();      // order P-adds before counter add
        int old = atomicAdd(&cnt[bx * 8 + by], 1);
        lastf = (old == 3) ? 1 : 0;
    }
    __syncthreads();
    if (lastf) {
        __threadfence();      // acquire: invalidate caches before reading P
        int r  = t >> 3;                  // 0..63
        int cg = (t & 7) * 8;             // 0..56
        int gi = bx * 64 + r;
        size_t base = (size_t)gi * NN + by * 64 + cg;

        float4 p0 = *(const float4*)&P[base];
        float4 p1 = *(const float4*)&P[base + 4];
        float4 n0 = *(const float4*)&noise[base];
        float4 n1 = *(const float4*)&noise[base + 4];

        float pv[8] = {p0.x, p0.y, p0.z, p0.w, p1.x, p1.y, p1.z, p1.w};
        float nv[8] = {n0.x, n0.y, n0.z, n0.w, n1.x, n1.y, n1.z, n1.w};
        float ov[8];
#pragma unroll
        for (int c = 0; c < 8; ++c) {
            float p = 0.25f * pv[c];
            int gj = by * 64 + cg + c;
            if (gj == gi) p = 0.0f;
            float lp = logf(p + 1e-10f) - log1pf(-p + 1e-10f);
            lp = fminf(fmaxf(lp, -10.0f), 10.0f);
            float lgs = logf(nv[c]) - log1pf(-nv[c]);
            ov[c] = 1.0f / (1.0f + expf(-(lp + lgs) * 5.0f));
        }
        *(float4*)&out[base]     = make_float4(ov[0], ov[1], ov[2], ov[3]);
        *(float4*)&out[base + 4] = make_float4(ov[4], ov[5], ov[6], ov[7]);
    }
}

// ---------------------------------------------------------------------------
extern "C" void kernel_launch(void* const* d_in, const int* in_sizes, int n_in,
                              void* d_out, int out_size, void* d_ws, size_t ws_size,
                              hipStream_t stream) {
    const float* x     = (const float*)d_in[0];
    const float* W1    = (const float*)d_in[1];
    const float* b1    = (const float*)d_in[2];
    const float* W2    = (const float*)d_in[3];
    const float* b2    = (const float*)d_in[4];
    const float* Wp    = (const float*)d_in[5];
    const float* bp    = (const float*)d_in[6];
    const float* Wb    = (const float*)d_in[7];
    const float* bb    = (const float*)d_in[8];
    const float* noise = (const float*)d_in[9];

    float* ws   = (float*)d_ws;
    float* S12  = ws;                 // 524288 floats
    float* Aarr = ws + 524288;        // 2048
    float* Carr = Aarr + 2048;        // 2048
    float* P    = Carr + 2048;        // 262144
    int*   cnt  = (int*)(P + 262144); // 64 ints

    kP<<<256, 512, 0, stream>>>(x, W1, b1, W2, b2, Wp, bp, Wb, bb,
                                S12, Aarr, Carr, P, cnt);
    kQ<<<dim3(8, 8, 4), 512, 0, stream>>>(S12, Aarr, Carr, Wb, noise,
                                          P, cnt, (float*)d_out);
}

// Round 5
// 79.535 us; speedup vs baseline: 1.3286x; 1.0106x over previous
//
#include <hip/hip_runtime.h>
#include <hip/hip_bf16.h>
#include <math.h>

// B=4, N=512, T=288, L=128
#define NN 512

// ---------------------------------------------------------------------------
// Kernel P: x -> x1,x2 (leaky) -> S12=[S1|S2] + row dots A,C.
// 256 blocks x 512 threads = (col 0..255, kh 0..1). 8 bn-rows per block.
// W staged in COALESCED un-transposed chunks Wt[512][17] (16 k's per half);
// per-col W read from LDS (odd stride -> conflict-free); x / x12 read with
// wave-uniform global addresses (1 cache line per instr).
// x12 round-trips through global scratch x12g (aliases PS4[0..512K)).
// ---------------------------------------------------------------------------
__global__ __launch_bounds__(512) void kP(
    const float* __restrict__ x,   // [2048][288]
    const float* __restrict__ W1,  // [128][288]
    const float* __restrict__ b1,  // [128]
    const float* __restrict__ W2,  // [128][288]
    const float* __restrict__ b2,  // [128]
    const float* __restrict__ Wp,  // [128][256]
    const float* __restrict__ bp,  // [128]
    const float* __restrict__ Wb,  // [128]
    const float* __restrict__ bb,  // [1]
    float* __restrict__ S12,       // ws [2048][256]
    float* __restrict__ Aarr,      // ws [2048]
    float* __restrict__ Carr,      // ws [2048]
    float* __restrict__ x12g,      // ws scratch [2048][256] (aliases PS4)
    int*   __restrict__ cnt)       // ws [64] (zeroed here for kQ)
{
    __shared__ __align__(16) float Wt[512][17];   // 34.8 KB
    __shared__ __align__(16) float ph[8 * 256];   // 8 KB
    __shared__ __align__(16) float s12s[8 * 257]; // 8.2 KB

    const int t   = threadIdx.x;
    const int bn0 = blockIdx.x * 8;
    const int col = t & 255;
    const int kh  = t >> 8;

    if (blockIdx.x == 0 && t < 64) cnt[t] = 0;

    // ---- G1: col of [x1|x2] for 8 rows; K=288 split 144/144 over kh ----
    float acc[8];
#pragma unroll
    for (int n = 0; n < 8; ++n) acc[n] = 0.0f;

    const float* xb = x + (size_t)bn0 * 288 + kh * 144;   // wave-uniform base

    for (int c = 0; c < 9; ++c) {       // 9 chunks of 16 k per half
        // stage W chunk, coalesced: lanes walk k within a row
#pragma unroll
        for (int i = 0; i < 4; ++i) {
            int task = i * 512 + t;     // float4 task 0..2047
            int k4   = task & 3;
            int rp   = task >> 2;       // 0..511
            int r    = rp & 255;
            int half = rp >> 8;
            int gk   = half * 144 + c * 16 + k4 * 4;
            const float* wr = (r < 128) ? (W1 + (size_t)r * 288 + gk)
                                        : (W2 + (size_t)(r - 128) * 288 + gk);
            *(float4*)&Wt[rp][k4 * 4] = *(const float4*)wr;
        }
        __syncthreads();

#pragma unroll
        for (int k4 = 0; k4 < 4; ++k4) {
            float4 w = *(const float4*)&Wt[kh * 256 + col][k4 * 4];
#pragma unroll
            for (int n = 0; n < 8; ++n) {
                float4 xv = *(const float4*)&xb[n * 288 + c * 16 + k4 * 4];
                acc[n] = fmaf(w.x, xv.x, acc[n]);
                acc[n] = fmaf(w.y, xv.y, acc[n]);
                acc[n] = fmaf(w.z, xv.z, acc[n]);
                acc[n] = fmaf(w.w, xv.w, acc[n]);
            }
        }
        __syncthreads();
    }

    const float bias1 = (col < 128) ? b1[col] : b2[col - 128];
    if (kh) {
#pragma unroll
        for (int n = 0; n < 8; ++n) ph[n * 256 + col] = acc[n];
    }
    __syncthreads();
    if (!kh) {
#pragma unroll
        for (int n = 0; n < 8; ++n) {
            float v = acc[n] + ph[n * 256 + col] + bias1;
            x12g[(size_t)(bn0 + n) * 256 + col] = fmaxf(v, 0.2f * v);  // leaky
        }
    }
    __syncthreads();   // drains stores -> x12g visible via L2 (same CU)

    // ---- G2: col of [S1|S2] for 8 rows; logical K=128 split 64/64 ----
    float acc2[8];
#pragma unroll
    for (int n = 0; n < 8; ++n) acc2[n] = 0.0f;

    const float* x2b = x12g + (size_t)bn0 * 256 + ((col < 128) ? 0 : 128) + kh * 64;

    for (int c = 0; c < 4; ++c) {       // 4 chunks of 16 k per half
#pragma unroll
        for (int i = 0; i < 4; ++i) {
            int task = i * 512 + t;
            int k4   = task & 3;
            int rp   = task >> 2;
            int r    = rp & 255;
            int half = rp >> 8;
            int gk   = half * 64 + c * 16 + k4 * 4;
            const float* wr = (r < 128) ? (Wp + (size_t)r * 256 + gk)
                                        : (Wp + (size_t)(r - 128) * 256 + 128 + gk);
            *(float4*)&Wt[rp][k4 * 4] = *(const float4*)wr;
        }
        __syncthreads();

#pragma unroll
        for (int k4 = 0; k4 < 4; ++k4) {
            float4 w = *(const float4*)&Wt[kh * 256 + col][k4 * 4];
#pragma unroll
            for (int n = 0; n < 8; ++n) {
                float4 xv = *(const float4*)&x2b[n * 256 + c * 16 + k4 * 4];
                acc2[n] = fmaf(w.x, xv.x, acc2[n]);
                acc2[n] = fmaf(w.y, xv.y, acc2[n]);
                acc2[n] = fmaf(w.z, xv.z, acc2[n]);
                acc2[n] = fmaf(w.w, xv.w, acc2[n]);
            }
        }
        __syncthreads();
    }

    const float bias2 = (col < 128) ? bp[col] : 0.0f;
    if (kh) {
#pragma unroll
        for (int n = 0; n < 8; ++n) ph[n * 256 + col] = acc2[n];
    }
    __syncthreads();
    if (!kh) {
#pragma unroll
        for (int n = 0; n < 8; ++n) {
            float sv = acc2[n] + ph[n * 256 + col] + bias2;
            S12[(size_t)(bn0 + n) * 256 + col] = sv;
            s12s[n * 257 + col] = sv;
        }
    }
    __syncthreads();

    // ---- per-row dots with Wb: 16 dots x 32 lanes ----
    {
        int lane32 = t & 31;
        int n = (t >> 5) & 7;
        int isC = t >> 8;
        int base = isC ? 128 : 0;
        float sum = 0.0f;
#pragma unroll
        for (int s = 0; s < 4; ++s) {
            int j = lane32 + s * 32;
            sum = fmaf(s12s[n * 257 + base + j], Wb[j], sum);
        }
#pragma unroll
        for (int m = 16; m >= 1; m >>= 1)
            sum += __shfl_xor(sum, m, 32);
        if (lane32 == 0) {
            if (isC) Carr[bn0 + n] = 0.6f * sum;
            else     Aarr[bn0 + n] = 0.6f * sum + bb[0];
        }
    }
}

// ---------------------------------------------------------------------------
// Kernel Q: pairwise acc(i,j) = sum_l |S1[i][l]+S2[j][l]|*Wb[l] -> sigmoid,
// stored to per-bz PS4 slice (agent-scope stores). Per-(bx,by) counter:
// 4th-arriving block re-reads the 4 slices and does phase F -> out.
// LDS tiles [l][i] stride 68: writes spread over banks via 4l, reads clean.
// ---------------------------------------------------------------------------
__global__ __launch_bounds__(512) void kQ(
    const float* __restrict__ S12,   // [2048][256]
    const float* __restrict__ Aarr,  // [2048]
    const float* __restrict__ Carr,  // [2048]
    const float* __restrict__ Wb,    // [128]
    const float* __restrict__ noise, // [512][512]
    float* __restrict__ PS4,         // ws [4][512][512]
    int*   __restrict__ cnt,         // ws [64] (pre-zeroed by kP)
    float* __restrict__ out)         // [512][512]
{
    __shared__ __align__(16) float S1t[128 * 68];   // 34.8 KB
    __shared__ __align__(16) float S2t[128 * 68];   // 34.8 KB
    __shared__ __align__(16) float wbs[128];
    __shared__ int lastf;

    const int t = threadIdx.x;
    const int bx = blockIdx.x, by = blockIdx.y, bz = blockIdx.z;
    const int ibn0 = bz * NN + bx * 64;
    const int jbn0 = bz * NN + by * 64;

    if (t < 32) *(float4*)&wbs[t * 4] = *(const float4*)&Wb[t * 4];

    // stage both tiles (64 rows x 128 l), transposed + XOR swizzle, stride 68
#pragma unroll
    for (int q = 0; q < 4; ++q) {
        int idx = q * 512 + t;      // float4 index 0..2047
        int row = idx >> 5;         // 0..63
        int c4 = idx & 31;          // l = c4*4+d
        float4 v1 = *(const float4*)&S12[(size_t)(ibn0 + row) * 256 + c4 * 4];
        float4 v2 = *(const float4*)&S12[(size_t)(jbn0 + row) * 256 + 128 + c4 * 4];
        float a1[4] = {v1.x, v1.y, v1.z, v1.w};
        float a2[4] = {v2.x, v2.y, v2.z, v2.w};
#pragma unroll
        for (int d = 0; d < 4; ++d) {
            int l = c4 * 4 + d;
            int sw = ((l >> 2) & 15) << 2;
            S1t[l * 68 + (row ^ sw)] = a1[d];
            S2t[l * 68 + (row ^ sw)] = a2[d];
        }
    }
    __syncthreads();

    const int tid = t & 255;
    const int lh = t >> 8;                 // l-half
    const int tx = tid & 15, ty = tid >> 4;
    const int i0 = ty * 4, j0 = tx * 4;
    const int lbase = lh * 64;

    float accv[16];
#pragma unroll
    for (int k = 0; k < 16; ++k) accv[k] = 0.0f;

    for (int l4 = 0; l4 < 16; ++l4) {
        const int sw = l4 << 2;            // == ((l>>2)&15)<<2 on both halves
        const int lrow = (lbase + l4 * 4) * 68;
        float4 wv = *(const float4*)&wbs[lbase + l4 * 4];
        const float wl[4] = {wv.x, wv.y, wv.z, wv.w};
#pragma unroll
        for (int d = 0; d < 4; ++d) {
            float4 a = *(const float4*)&S1t[lrow + d * 68 + (i0 ^ sw)];
            float4 b = *(const float4*)&S2t[lrow + d * 68 + (j0 ^ sw)];
            float w = wl[d];
            float ai[4] = {a.x, a.y, a.z, a.w};
            float bj[4] = {b.x, b.y, b.z, b.w};
#pragma unroll
            for (int ii = 0; ii < 4; ++ii)
#pragma unroll
                for (int jj = 0; jj < 4; ++jj) {
                    float tv = ai[ii] + bj[jj];
                    accv[ii * 4 + jj] = fmaf(fabsf(tv), w, accv[ii * 4 + jj]);
                }
        }
    }

    // cross-reduce the two l-halves through LDS (alias onto S1t)
    float* red = S1t;
    __syncthreads();
    if (lh) {
#pragma unroll
        for (int q = 0; q < 4; ++q) {
            float4 v = {accv[4 * q], accv[4 * q + 1], accv[4 * q + 2], accv[4 * q + 3]};
            *(float4*)&red[q * 1024 + tid * 4] = v;
        }
    }
    __syncthreads();
    if (!lh) {
#pragma unroll
        for (int q = 0; q < 4; ++q) {
            float4 v = *(const float4*)&red[q * 1024 + tid * 4];
            accv[4 * q]     += v.x;
            accv[4 * q + 1] += v.y;
            accv[4 * q + 2] += v.z;
            accv[4 * q + 3] += v.w;
        }

        float Av[4], Cv[4];
#pragma unroll
        for (int ii = 0; ii < 4; ++ii) Av[ii] = Aarr[ibn0 + i0 + ii];
#pragma unroll
        for (int jj = 0; jj < 4; ++jj) Cv[jj] = Carr[jbn0 + j0 + jj];

#pragma unroll
        for (int ii = 0; ii < 4; ++ii) {
            size_t obase = (size_t)bz * (NN * NN) +
                           (size_t)(bx * 64 + i0 + ii) * NN + by * 64 + j0;
#pragma unroll
            for (int jj = 0; jj < 4; ++jj) {
                float lg = Av[ii] + Cv[jj] + 0.4f * accv[ii * 4 + jj];
                float sig = 1.0f / (1.0f + expf(-lg));
                // agent-scope store: lands at the device coherence point
                __hip_atomic_store(&PS4[obase + jj], sig,
                                   __ATOMIC_RELAXED, __HIP_MEMORY_SCOPE_AGENT);
            }
        }
    }

    // ---- last-arriver does phase F for this (bx,by) tile ----
    __syncthreads();          // all lanes' stores complete (vmcnt drained)
    if (t == 0) {
        __threadfence();
        int old = atomicAdd(&cnt[bx * 8 + by], 1);
        lastf = (old == 3) ? 1 : 0;
    }
    __syncthreads();
    if (lastf) {
        __threadfence();
        int r  = t >> 3;                  // 0..63
        int cg = (t & 7) * 8;             // 0..56
        int gi = bx * 64 + r;
        size_t base = (size_t)gi * NN + by * 64 + cg;

        float pv[8];
#pragma unroll
        for (int c = 0; c < 8; ++c) {
            float s = 0.0f;
#pragma unroll
            for (int bzz = 0; bzz < 4; ++bzz)
                s += __hip_atomic_load(&PS4[(size_t)bzz * (NN * NN) + base + c],
                                       __ATOMIC_RELAXED, __HIP_MEMORY_SCOPE_AGENT);
            pv[c] = s;
        }

        float4 n0 = *(const float4*)&noise[base];
        float4 n1 = *(const float4*)&noise[base + 4];
        float nv[8] = {n0.x, n0.y, n0.z, n0.w, n1.x, n1.y, n1.z, n1.w};
        float ov[8];
#pragma unroll
        for (int c = 0; c < 8; ++c) {
            float p = 0.25f * pv[c];
            int gj = by * 64 + cg + c;
            if (gj == gi) p = 0.0f;
            float lp = logf(p + 1e-10f) - log1pf(-p + 1e-10f);
            lp = fminf(fmaxf(lp, -10.0f), 10.0f);
            float lgs = logf(nv[c]) - log1pf(-nv[c]);
            ov[c] = 1.0f / (1.0f + expf(-(lp + lgs) * 5.0f));
        }
        *(float4*)&out[base]     = make_float4(ov[0], ov[1], ov[2], ov[3]);
        *(float4*)&out[base + 4] = make_float4(ov[4], ov[5], ov[6], ov[7]);
    }
}

// ---------------------------------------------------------------------------
extern "C" void kernel_launch(void* const* d_in, const int* in_sizes, int n_in,
                              void* d_out, int out_size, void* d_ws, size_t ws_size,
                              hipStream_t stream) {
    const float* x     = (const float*)d_in[0];
    const float* W1    = (const float*)d_in[1];
    const float* b1    = (const float*)d_in[2];
    const float* W2    = (const float*)d_in[3];
    const float* b2    = (const float*)d_in[4];
    const float* Wp    = (const float*)d_in[5];
    const float* bp    = (const float*)d_in[6];
    const float* Wb    = (const float*)d_in[7];
    const float* bb    = (const float*)d_in[8];
    const float* noise = (const float*)d_in[9];

    float* ws   = (float*)d_ws;
    float* S12  = ws;                   // 524288 floats
    float* Aarr = ws + 524288;          // 2048
    float* Carr = Aarr + 2048;          // 2048
    float* PS4  = Carr + 2048;          // 1048576 floats
    float* x12g = PS4;                  // scratch aliasing PS4[0..524288) — dead before kQ writes
    int*   cnt  = (int*)(PS4 + 1048576);// 64 ints

    kP<<<256, 512, 0, stream>>>(x, W1, b1, W2, b2, Wp, bp, Wb, bb,
                                S12, Aarr, Carr, x12g, cnt);
    kQ<<<dim3(8, 8, 4), 512, 0, stream>>>(S12, Aarr, Carr, Wb, noise,
                                          PS4, cnt, (float*)d_out);
}

// Round 6
// 59.064 us; speedup vs baseline: 1.7891x; 1.3466x over previous
//
#include <hip/hip_runtime.h>
#include <hip/hip_bf16.h>
#include <math.h>

// B=4, N=512, T=288, L=128
#define NN 512
#define NT 288

// ---------------------------------------------------------------------------
// Kernel P: x -> x1,x2 (leaky) -> S12=[S1|S2] + row dots A,C.
// 256 blocks x 512 threads = (col 0..255, kh 0..1), 8 bn-rows per block.
// W/Wp read per-lane directly from global (L2-resident, reused across blocks;
// no LDS staging — zero intra-block reuse makes staging pure overhead).
// x staged once in LDS, read as wave-broadcast. No barriers inside GEMM loops.
// ---------------------------------------------------------------------------
__global__ __launch_bounds__(512) void kP(
    const float* __restrict__ x,   // [2048][288]
    const float* __restrict__ W1,  // [128][288]
    const float* __restrict__ b1,  // [128]
    const float* __restrict__ W2,  // [128][288]
    const float* __restrict__ b2,  // [128]
    const float* __restrict__ Wp,  // [128][256]
    const float* __restrict__ bp,  // [128]
    const float* __restrict__ Wb,  // [128]
    const float* __restrict__ bb,  // [1]
    float* __restrict__ S12,       // ws [2048][256]
    float* __restrict__ Aarr,      // ws [2048]
    float* __restrict__ Carr,      // ws [2048]
    int*   __restrict__ cnt)       // ws [64] (zeroed here for kQ)
{
    __shared__ __align__(16) float xs[8 * NT];     // 9 KB; aliased s12s[8][257] later
    __shared__ __align__(16) float x12s[8 * 256];  // 8 KB
    __shared__ __align__(16) float ph[8 * 256];    // 8 KB

    const int t   = threadIdx.x;
    const int bn0 = blockIdx.x * 8;
    const int col = t & 255;
    const int kh  = t >> 8;       // K-half

    if (blockIdx.x == 0 && t < 64) cnt[t] = 0;

    // stage 8 x-rows (576 float4)
    for (int q = 0; q < 2; ++q) {
        int idx = q * 512 + t;
        if (idx < 576) {
            int row = idx / 72, c4 = idx % 72;
            *(float4*)&xs[row * NT + c4 * 4] =
                *(const float4*)&x[(size_t)(bn0 + row) * NT + c4 * 4];
        }
    }
    __syncthreads();

    // ---- G1: col of [x1|x2] for 8 rows; K=288 split 144/144 over kh ----
    const float* wrow = ((col < 128) ? (W1 + col * NT) : (W2 + (col - 128) * NT))
                        + kh * 144;
    const float bias1 = (col < 128) ? b1[col] : b2[col - 128];
    const int kb1 = kh * 144;

    float acc[8];
#pragma unroll
    for (int n = 0; n < 8; ++n) acc[n] = 0.0f;

    for (int k = 0; k < 144; k += 4) {
        float4 w = *(const float4*)(wrow + k);
#pragma unroll
        for (int n = 0; n < 8; ++n) {
            float4 xv = *(const float4*)&xs[n * NT + kb1 + k];
            acc[n] = fmaf(w.x, xv.x, acc[n]);
            acc[n] = fmaf(w.y, xv.y, acc[n]);
            acc[n] = fmaf(w.z, xv.z, acc[n]);
            acc[n] = fmaf(w.w, xv.w, acc[n]);
        }
    }
    if (kh) {
#pragma unroll
        for (int n = 0; n < 8; ++n) ph[n * 256 + col] = acc[n];
    }
    __syncthreads();
    if (!kh) {
#pragma unroll
        for (int n = 0; n < 8; ++n) {
            float v = acc[n] + ph[n * 256 + col] + bias1;
            x12s[n * 256 + col] = fmaxf(v, 0.2f * v);   // leaky
        }
    }
    __syncthreads();

    // ---- G2: col of [S1|S2] for 8 rows; K=128 split 64/64 over kh ----
    const int koff = (col < 128) ? 0 : 128;
    const float* wprow = ((col < 128) ? (Wp + col * 256) : (Wp + (col - 128) * 256 + 128))
                         + kh * 64;
    const float bias2 = (col < 128) ? bp[col] : 0.0f;
    const int kb2 = koff + kh * 64;

    float acc2[8];
#pragma unroll
    for (int n = 0; n < 8; ++n) acc2[n] = 0.0f;

    for (int k = 0; k < 64; k += 4) {
        float4 w = *(const float4*)(wprow + k);
#pragma unroll
        for (int n = 0; n < 8; ++n) {
            float4 xv = *(const float4*)&x12s[n * 256 + kb2 + k];
            acc2[n] = fmaf(w.x, xv.x, acc2[n]);
            acc2[n] = fmaf(w.y, xv.y, acc2[n]);
            acc2[n] = fmaf(w.z, xv.z, acc2[n]);
            acc2[n] = fmaf(w.w, xv.w, acc2[n]);
        }
    }
    if (kh) {
#pragma unroll
        for (int n = 0; n < 8; ++n) ph[n * 256 + col] = acc2[n];
    }
    __syncthreads();

    float* s12s = xs;   // alias: xs dead after G1
    if (!kh) {
#pragma unroll
        for (int n = 0; n < 8; ++n) {
            float sv = acc2[n] + ph[n * 256 + col] + bias2;
            S12[(size_t)(bn0 + n) * 256 + col] = sv;
            s12s[n * 257 + col] = sv;
        }
    }
    __syncthreads();

    // ---- per-row dots with Wb: 16 dots x 32 lanes ----
    {
        int lane32 = t & 31;
        int n = (t >> 5) & 7;
        int isC = t >> 8;
        int base = isC ? 128 : 0;
        float sum = 0.0f;
#pragma unroll
        for (int s = 0; s < 4; ++s) {
            int j = lane32 + s * 32;
            sum = fmaf(s12s[n * 257 + base + j], Wb[j], sum);
        }
#pragma unroll
        for (int m = 16; m >= 1; m >>= 1)
            sum += __shfl_xor(sum, m, 32);
        if (lane32 == 0) {
            if (isC) Carr[bn0 + n] = 0.6f * sum;
            else     Aarr[bn0 + n] = 0.6f * sum + bb[0];
        }
    }
}

// ---------------------------------------------------------------------------
// Kernel Q: pairwise acc(i,j) = sum_l |S1[i][l]+S2[j][l]|*Wb[l] -> sigmoid,
// stored to per-bz PS4 slice (agent-scope stores). Per-(bx,by) counter:
// 4th-arriving block re-reads the 4 slices and does fused phase F -> out.
// LDS tiles [l][i] stride 64 with XOR swizzle i^(((l>>2)&15)<<2):
// reads conflict-free, writes 4-way (acceptable, m136: 1.58x).
// ---------------------------------------------------------------------------
__global__ __launch_bounds__(512) void kQ(
    const float* __restrict__ S12,   // [2048][256]
    const float* __restrict__ Aarr,  // [2048]
    const float* __restrict__ Carr,  // [2048]
    const float* __restrict__ Wb,    // [128]
    const float* __restrict__ noise, // [512][512]
    float* __restrict__ PS4,         // ws [4][512][512]
    int*   __restrict__ cnt,         // ws [64] (pre-zeroed by kP)
    float* __restrict__ out)         // [512][512]
{
    __shared__ __align__(16) float S1t[128 * 64];   // 32 KB
    __shared__ __align__(16) float S2t[128 * 64];   // 32 KB
    __shared__ __align__(16) float wbs[128];
    __shared__ int lastf;

    const int t = threadIdx.x;
    const int bx = blockIdx.x, by = blockIdx.y, bz = blockIdx.z;
    const int ibn0 = bz * NN + bx * 64;
    const int jbn0 = bz * NN + by * 64;

    if (t < 32) *(float4*)&wbs[t * 4] = *(const float4*)&Wb[t * 4];

    // stage both tiles (64 rows x 128 l), transposed + XOR swizzle
#pragma unroll
    for (int q = 0; q < 4; ++q) {
        int idx = q * 512 + t;      // float4 index 0..2047
        int row = idx >> 5;         // 0..63
        int c4 = idx & 31;          // l = c4*4+d
        float4 v1 = *(const float4*)&S12[(size_t)(ibn0 + row) * 256 + c4 * 4];
        float4 v2 = *(const float4*)&S12[(size_t)(jbn0 + row) * 256 + 128 + c4 * 4];
        float a1[4] = {v1.x, v1.y, v1.z, v1.w};
        float a2[4] = {v2.x, v2.y, v2.z, v2.w};
#pragma unroll
        for (int d = 0; d < 4; ++d) {
            int l = c4 * 4 + d;
            int sw = ((l >> 2) & 15) << 2;
            S1t[l * 64 + (row ^ sw)] = a1[d];
            S2t[l * 64 + (row ^ sw)] = a2[d];
        }
    }
    __syncthreads();

    const int tid = t & 255;
    const int lh = t >> 8;                 // l-half
    const int tx = tid & 15, ty = tid >> 4;
    const int i0 = ty * 4, j0 = tx * 4;
    const int lbase = lh * 64;

    float accv[16];
#pragma unroll
    for (int k = 0; k < 16; ++k) accv[k] = 0.0f;

    for (int l4 = 0; l4 < 16; ++l4) {
        const int sw = l4 << 2;            // == ((l>>2)&15)<<2 on both halves
        const int lrow = (lbase + l4 * 4) * 64;
        float4 wv = *(const float4*)&wbs[lbase + l4 * 4];
        const float wl[4] = {wv.x, wv.y, wv.z, wv.w};
#pragma unroll
        for (int d = 0; d < 4; ++d) {
            float4 a = *(const float4*)&S1t[lrow + d * 64 + (i0 ^ sw)];
            float4 b = *(const float4*)&S2t[lrow + d * 64 + (j0 ^ sw)];
            float w = wl[d];
            float ai[4] = {a.x, a.y, a.z, a.w};
            float bj[4] = {b.x, b.y, b.z, b.w};
#pragma unroll
            for (int ii = 0; ii < 4; ++ii)
#pragma unroll
                for (int jj = 0; jj < 4; ++jj) {
                    float tv = ai[ii] + bj[jj];
                    accv[ii * 4 + jj] = fmaf(fabsf(tv), w, accv[ii * 4 + jj]);
                }
        }
    }

    // cross-reduce the two l-halves through LDS (alias onto S1t)
    float* red = S1t;
    __syncthreads();
    if (lh) {
#pragma unroll
        for (int q = 0; q < 4; ++q) {
            float4 v = {accv[4 * q], accv[4 * q + 1], accv[4 * q + 2], accv[4 * q + 3]};
            *(float4*)&red[q * 1024 + tid * 4] = v;
        }
    }
    __syncthreads();
    if (!lh) {
#pragma unroll
        for (int q = 0; q < 4; ++q) {
            float4 v = *(const float4*)&red[q * 1024 + tid * 4];
            accv[4 * q]     += v.x;
            accv[4 * q + 1] += v.y;
            accv[4 * q + 2] += v.z;
            accv[4 * q + 3] += v.w;
        }

        float Av[4], Cv[4];
#pragma unroll
        for (int ii = 0; ii < 4; ++ii) Av[ii] = Aarr[ibn0 + i0 + ii];
#pragma unroll
        for (int jj = 0; jj < 4; ++jj) Cv[jj] = Carr[jbn0 + j0 + jj];

#pragma unroll
        for (int ii = 0; ii < 4; ++ii) {
            size_t obase = (size_t)bz * (NN * NN) +
                           (size_t)(bx * 64 + i0 + ii) * NN + by * 64 + j0;
#pragma unroll
            for (int jj = 0; jj < 4; ++jj) {
                float lg = Av[ii] + Cv[jj] + 0.4f * accv[ii * 4 + jj];
                float sig = 1.0f / (1.0f + expf(-lg));
                __hip_atomic_store(&PS4[obase + jj], sig,
                                   __ATOMIC_RELAXED, __HIP_MEMORY_SCOPE_AGENT);
            }
        }
    }

    // ---- last-arriver does fused phase F for this (bx,by) tile ----
    __syncthreads();          // all waves' stores drained (vmcnt(0) at barrier)
    if (t == 0) {
        __threadfence();      // release P-stores before counter bump
        int old = atomicAdd(&cnt[bx * 8 + by], 1);
        lastf = (old == 3) ? 1 : 0;
    }
    __syncthreads();
    if (lastf) {
        __threadfence();      // acquire
        int r  = t >> 3;                  // 0..63
        int cg = (t & 7) * 8;             // 0..56
        int gi = bx * 64 + r;
        size_t base = (size_t)gi * NN + by * 64 + cg;

        float pv[8];
#pragma unroll
        for (int c = 0; c < 8; ++c) {
            float s = 0.0f;
#pragma unroll
            for (int bzz = 0; bzz < 4; ++bzz)
                s += __hip_atomic_load(&PS4[(size_t)bzz * (NN * NN) + base + c],
                                       __ATOMIC_RELAXED, __HIP_MEMORY_SCOPE_AGENT);
            pv[c] = s;
        }

        float4 n0 = *(const float4*)&noise[base];
        float4 n1 = *(const float4*)&noise[base + 4];
        float nv[8] = {n0.x, n0.y, n0.z, n0.w, n1.x, n1.y, n1.z, n1.w};
        float ov[8];
#pragma unroll
        for (int c = 0; c < 8; ++c) {
            float p = 0.25f * pv[c];
            int gj = by * 64 + cg + c;
            if (gj == gi) p = 0.0f;
            float lp = logf(p + 1e-10f) - log1pf(-p + 1e-10f);
            lp = fminf(fmaxf(lp, -10.0f), 10.0f);
            float lgs = logf(nv[c]) - log1pf(-nv[c]);
            ov[c] = 1.0f / (1.0f + expf(-(lp + lgs) * 5.0f));
        }
        *(float4*)&out[base]     = make_float4(ov[0], ov[1], ov[2], ov[3]);
        *(float4*)&out[base + 4] = make_float4(ov[4], ov[5], ov[6], ov[7]);
    }
}

// ---------------------------------------------------------------------------
extern "C" void kernel_launch(void* const* d_in, const int* in_sizes, int n_in,
                              void* d_out, int out_size, void* d_ws, size_t ws_size,
                              hipStream_t stream) {
    const float* x     = (const float*)d_in[0];
    const float* W1    = (const float*)d_in[1];
    const float* b1    = (const float*)d_in[2];
    const float* W2    = (const float*)d_in[3];
    const float* b2    = (const float*)d_in[4];
    const float* Wp    = (const float*)d_in[5];
    const float* bp    = (const float*)d_in[6];
    const float* Wb    = (const float*)d_in[7];
    const float* bb    = (const float*)d_in[8];
    const float* noise = (const float*)d_in[9];

    float* ws   = (float*)d_ws;
    float* S12  = ws;                   // 524288 floats
    float* Aarr = ws + 524288;          // 2048
    float* Carr = Aarr + 2048;          // 2048
    float* PS4  = Carr + 2048;          // 1048576 floats
    int*   cnt  = (int*)(PS4 + 1048576);// 64 ints

    kP<<<256, 512, 0, stream>>>(x, W1, b1, W2, b2, Wp, bp, Wb, bb,
                                S12, Aarr, Carr, cnt);
    kQ<<<dim3(8, 8, 4), 512, 0, stream>>>(S12, Aarr, Carr, Wb, noise,
                                          PS4, cnt, (float*)d_out);
}

// Round 7
// 43.622 us; speedup vs baseline: 2.4224x; 1.3540x over previous
//
#include <hip/hip_runtime.h>
#include <hip/hip_bf16.h>
#include <math.h>

// B=4, N=512, T=288, L=128
#define NN 512
#define NT 288

// ---------------------------------------------------------------------------
// Kernel P: x -> x1,x2 (leaky) -> S12=[S1|S2] + row dots A,C.
// 256 blocks x 512 threads = (col 0..255, kh 0..1), 8 bn-rows per block.
// W/Wp per-lane direct from global (L2-resident); x staged in LDS once.
// ---------------------------------------------------------------------------
__global__ __launch_bounds__(512) void kP(
    const float* __restrict__ x,   // [2048][288]
    const float* __restrict__ W1,  // [128][288]
    const float* __restrict__ b1,  // [128]
    const float* __restrict__ W2,  // [128][288]
    const float* __restrict__ b2,  // [128]
    const float* __restrict__ Wp,  // [128][256]
    const float* __restrict__ bp,  // [128]
    const float* __restrict__ Wb,  // [128]
    const float* __restrict__ bb,  // [1]
    float* __restrict__ S12,       // ws [2048][256]
    float* __restrict__ Aarr,      // ws [2048]
    float* __restrict__ Carr)      // ws [2048]
{
    __shared__ __align__(16) float xs[8 * NT];     // 9 KB; aliased s12s[8][257] later
    __shared__ __align__(16) float x12s[8 * 256];  // 8 KB
    __shared__ __align__(16) float ph[8 * 256];    // 8 KB

    const int t   = threadIdx.x;
    const int bn0 = blockIdx.x * 8;
    const int col = t & 255;
    const int kh  = t >> 8;       // K-half

    // stage 8 x-rows (576 float4)
    for (int q = 0; q < 2; ++q) {
        int idx = q * 512 + t;
        if (idx < 576) {
            int row = idx / 72, c4 = idx % 72;
            *(float4*)&xs[row * NT + c4 * 4] =
                *(const float4*)&x[(size_t)(bn0 + row) * NT + c4 * 4];
        }
    }
    __syncthreads();

    // ---- G1: col of [x1|x2] for 8 rows; K=288 split 144/144 over kh ----
    const float* wrow = ((col < 128) ? (W1 + col * NT) : (W2 + (col - 128) * NT))
                        + kh * 144;
    const float bias1 = (col < 128) ? b1[col] : b2[col - 128];
    const int kb1 = kh * 144;

    float acc[8];
#pragma unroll
    for (int n = 0; n < 8; ++n) acc[n] = 0.0f;

    for (int k = 0; k < 144; k += 4) {
        float4 w = *(const float4*)(wrow + k);
#pragma unroll
        for (int n = 0; n < 8; ++n) {
            float4 xv = *(const float4*)&xs[n * NT + kb1 + k];
            acc[n] = fmaf(w.x, xv.x, acc[n]);
            acc[n] = fmaf(w.y, xv.y, acc[n]);
            acc[n] = fmaf(w.z, xv.z, acc[n]);
            acc[n] = fmaf(w.w, xv.w, acc[n]);
        }
    }
    if (kh) {
#pragma unroll
        for (int n = 0; n < 8; ++n) ph[n * 256 + col] = acc[n];
    }
    __syncthreads();
    if (!kh) {
#pragma unroll
        for (int n = 0; n < 8; ++n) {
            float v = acc[n] + ph[n * 256 + col] + bias1;
            x12s[n * 256 + col] = fmaxf(v, 0.2f * v);   // leaky
        }
    }
    __syncthreads();

    // ---- G2: col of [S1|S2] for 8 rows; K=128 split 64/64 over kh ----
    const int koff = (col < 128) ? 0 : 128;
    const float* wprow = ((col < 128) ? (Wp + col * 256) : (Wp + (col - 128) * 256 + 128))
                         + kh * 64;
    const float bias2 = (col < 128) ? bp[col] : 0.0f;
    const int kb2 = koff + kh * 64;

    float acc2[8];
#pragma unroll
    for (int n = 0; n < 8; ++n) acc2[n] = 0.0f;

    for (int k = 0; k < 64; k += 4) {
        float4 w = *(const float4*)(wprow + k);
#pragma unroll
        for (int n = 0; n < 8; ++n) {
            float4 xv = *(const float4*)&x12s[n * 256 + kb2 + k];
            acc2[n] = fmaf(w.x, xv.x, acc2[n]);
            acc2[n] = fmaf(w.y, xv.y, acc2[n]);
            acc2[n] = fmaf(w.z, xv.z, acc2[n]);
            acc2[n] = fmaf(w.w, xv.w, acc2[n]);
        }
    }
    if (kh) {
#pragma unroll
        for (int n = 0; n < 8; ++n) ph[n * 256 + col] = acc2[n];
    }
    __syncthreads();

    float* s12s = xs;   // alias: xs dead after G1
    if (!kh) {
#pragma unroll
        for (int n = 0; n < 8; ++n) {
            float sv = acc2[n] + ph[n * 256 + col] + bias2;
            S12[(size_t)(bn0 + n) * 256 + col] = sv;
            s12s[n * 257 + col] = sv;
        }
    }
    __syncthreads();

    // ---- per-row dots with Wb: 16 dots x 32 lanes ----
    {
        int lane32 = t & 31;
        int n = (t >> 5) & 7;
        int isC = t >> 8;
        int base = isC ? 128 : 0;
        float sum = 0.0f;
#pragma unroll
        for (int s = 0; s < 4; ++s) {
            int j = lane32 + s * 32;
            sum = fmaf(s12s[n * 257 + base + j], Wb[j], sum);
        }
#pragma unroll
        for (int m = 16; m >= 1; m >>= 1)
            sum += __shfl_xor(sum, m, 32);
        if (lane32 == 0) {
            if (isC) Carr[bn0 + n] = 0.6f * sum;
            else     Aarr[bn0 + n] = 0.6f * sum + bb[0];
        }
    }
}

// ---------------------------------------------------------------------------
// Kernel Q: fully-fused pairwise + mean-over-b + phase F.
// grid (16,16) = 32x32 output tile per block; ALL 4 b-slices in one block.
// 512 threads = (lh 0..1, bz 0..3, s 0..63); 4x4 outputs per (bz,s) thread.
// LDS: S1t[4][128][32] + S2t[4][128][32] = 128 KB (transposed, XOR-swizzled
// i^(((l>>2)&7)<<2): staging writes 4-way, main-loop reads conflict-free).
// Reductions (l-halves, then bz, then redistribute) alias the dead S1t.
// Only global write: out (1 MB). No atomics, no workspace roundtrip.
// ---------------------------------------------------------------------------
__global__ __launch_bounds__(512) void kQ(
    const float* __restrict__ S12,   // [2048][256]
    const float* __restrict__ Aarr,  // [2048]
    const float* __restrict__ Carr,  // [2048]
    const float* __restrict__ Wb,    // [128]
    const float* __restrict__ noise, // [512][512]
    float* __restrict__ out)         // [512][512]
{
    __shared__ __align__(16) float smem[32768];   // 128 KB
    float* S1t = smem;             // [4][128][32]
    float* S2t = smem + 16384;     // [4][128][32]

    const int t = threadIdx.x;
    const int bx = blockIdx.x, by = blockIdx.y;

    // ---- stage all 4 bz tiles: 8192 float4 tasks, 16 per thread ----
#pragma unroll
    for (int q = 0; q < 16; ++q) {
        int task = q * 512 + t;
        int isS2 = task >> 12;
        int r    = task & 4095;
        int bz   = r >> 10;
        int row  = (r >> 5) & 31;
        int c4   = r & 31;
        size_t src = (size_t)(bz * NN + (isS2 ? by : bx) * 32 + row) * 256
                     + (isS2 ? 128 : 0) + c4 * 4;
        float4 v = *(const float4*)&S12[src];
        float* dst = (isS2 ? S2t : S1t) + bz * 4096;
        int rw = row ^ ((c4 & 7) << 2);          // sw = ((l>>2)&7)<<2, l = 4c4+d
        dst[(c4 * 4 + 0) * 32 + rw] = v.x;
        dst[(c4 * 4 + 1) * 32 + rw] = v.y;
        dst[(c4 * 4 + 2) * 32 + rw] = v.z;
        dst[(c4 * 4 + 3) * 32 + rw] = v.w;
    }
    __syncthreads();

    const int lh = t >> 8;           // l-half
    const int bz = (t >> 6) & 3;     // b-slice (wave-uniform)
    const int s  = t & 63;
    const int i0 = (s >> 3) << 2, j0 = (s & 7) << 2;

    const float* S1b = S1t + bz * 4096 + lh * 64 * 32;
    const float* S2b = S2t + bz * 4096 + lh * 64 * 32;
    const float* wbp = Wb + lh * 64;

    float accv[16];
#pragma unroll
    for (int k = 0; k < 16; ++k) accv[k] = 0.0f;

    for (int l4 = 0; l4 < 16; ++l4) {
        const int sw = (l4 & 7) << 2;
        const int lrow = l4 * 4 * 32;
        float4 wv = *(const float4*)&wbp[l4 * 4];   // wave-uniform broadcast
        const float wl[4] = {wv.x, wv.y, wv.z, wv.w};
#pragma unroll
        for (int d = 0; d < 4; ++d) {
            float4 a = *(const float4*)&S1b[lrow + d * 32 + (i0 ^ sw)];
            float4 b = *(const float4*)&S2b[lrow + d * 32 + (j0 ^ sw)];
            float w = wl[d];
            float ai[4] = {a.x, a.y, a.z, a.w};
            float bj[4] = {b.x, b.y, b.z, b.w};
#pragma unroll
            for (int ii = 0; ii < 4; ++ii)
#pragma unroll
                for (int jj = 0; jj < 4; ++jj) {
                    float tv = ai[ii] + bj[jj];
                    accv[ii * 4 + jj] = fmaf(fabsf(tv), w, accv[ii * 4 + jj]);
                }
        }
    }

    // ---- reduce l-halves through LDS (alias dead S1t) ----
    float* red = smem;                    // 4096 floats
    const int tid2 = t & 255;             // (bz, s)
    __syncthreads();
    if (lh) {
#pragma unroll
        for (int q = 0; q < 4; ++q) {
            float4 v = {accv[4 * q], accv[4 * q + 1], accv[4 * q + 2], accv[4 * q + 3]};
            *(float4*)&red[q * 1024 + tid2 * 4] = v;
        }
    }
    __syncthreads();

    float sig[16];
    if (!lh) {
#pragma unroll
        for (int q = 0; q < 4; ++q) {
            float4 v = *(const float4*)&red[q * 1024 + tid2 * 4];
            accv[4 * q]     += v.x;
            accv[4 * q + 1] += v.y;
            accv[4 * q + 2] += v.z;
            accv[4 * q + 3] += v.w;
        }
        float Av[4], Cv[4];
#pragma unroll
        for (int ii = 0; ii < 4; ++ii) Av[ii] = Aarr[bz * NN + bx * 32 + i0 + ii];
#pragma unroll
        for (int jj = 0; jj < 4; ++jj) Cv[jj] = Carr[bz * NN + by * 32 + j0 + jj];
#pragma unroll
        for (int ii = 0; ii < 4; ++ii)
#pragma unroll
            for (int jj = 0; jj < 4; ++jj) {
                float lg = Av[ii] + Cv[jj] + 0.4f * accv[ii * 4 + jj];
                sig[ii * 4 + jj] = 1.0f / (1.0f + expf(-lg));
            }
        // ---- bz-reduce staging: bz>=1 write sigmoids ----
        float* redB = smem + 4096;        // 3072 floats
        if (bz) {
#pragma unroll
            for (int q = 0; q < 4; ++q) {
                float4 v = {sig[4 * q], sig[4 * q + 1], sig[4 * q + 2], sig[4 * q + 3]};
                *(float4*)&redB[(bz - 1) * 1024 + q * 256 + s * 4] = v;
            }
        }
    }
    __syncthreads();

    // ---- bz=0 threads sum 4 slices, publish p[16] ----
    float* redB = smem + 4096;
    float* redP = smem + 7168;            // 1024 floats
    if (t < 64) {                          // lh=0, bz=0, s=t
#pragma unroll
        for (int bzz = 0; bzz < 3; ++bzz)
#pragma unroll
            for (int q = 0; q < 4; ++q) {
                float4 v = *(const float4*)&redB[bzz * 1024 + q * 256 + t * 4];
                sig[4 * q]     += v.x;
                sig[4 * q + 1] += v.y;
                sig[4 * q + 2] += v.z;
                sig[4 * q + 3] += v.w;
            }
#pragma unroll
        for (int q = 0; q < 4; ++q) {
            float4 v = {sig[4 * q], sig[4 * q + 1], sig[4 * q + 2], sig[4 * q + 3]};
            *(float4*)&redP[t * 16 + q * 4] = v;
        }
    }
    __syncthreads();

    // ---- phase F: 256 threads, 4 outputs each ----
    if (t < 256) {
        int i   = t >> 3;                 // 0..31
        int j0f = (t & 7) * 4;            // 0..28
        int sP  = (t >> 5) * 8 + (t & 7);
        int k0  = ((t >> 3) & 3) * 4;
        float4 pv4 = *(const float4*)&redP[sP * 16 + k0];
        float pv[4] = {pv4.x, pv4.y, pv4.z, pv4.w};

        int gi = bx * 32 + i;
        size_t base = (size_t)gi * NN + by * 32 + j0f;
        float4 nz = *(const float4*)&noise[base];
        float nv[4] = {nz.x, nz.y, nz.z, nz.w};

        float4 o;
        float* op = (float*)&o;
#pragma unroll
        for (int c = 0; c < 4; ++c) {
            float p = 0.25f * pv[c];
            int gj = by * 32 + j0f + c;
            if (gj == gi) p = 0.0f;
            float lp = logf(p + 1e-10f) - log1pf(-p + 1e-10f);
            lp = fminf(fmaxf(lp, -10.0f), 10.0f);
            float lgs = logf(nv[c]) - log1pf(-nv[c]);
            op[c] = 1.0f / (1.0f + expf(-(lp + lgs) * 5.0f));
        }
        *(float4*)&out[base] = o;
    }
}

// ---------------------------------------------------------------------------
extern "C" void kernel_launch(void* const* d_in, const int* in_sizes, int n_in,
                              void* d_out, int out_size, void* d_ws, size_t ws_size,
                              hipStream_t stream) {
    const float* x     = (const float*)d_in[0];
    const float* W1    = (const float*)d_in[1];
    const float* b1    = (const float*)d_in[2];
    const float* W2    = (const float*)d_in[3];
    const float* b2    = (const float*)d_in[4];
    const float* Wp    = (const float*)d_in[5];
    const float* bp    = (const float*)d_in[6];
    const float* Wb    = (const float*)d_in[7];
    const float* bb    = (const float*)d_in[8];
    const float* noise = (const float*)d_in[9];

    float* ws   = (float*)d_ws;
    float* S12  = ws;                   // 524288 floats
    float* Aarr = ws + 524288;          // 2048
    float* Carr = Aarr + 2048;          // 2048

    kP<<<256, 512, 0, stream>>>(x, W1, b1, W2, b2, Wp, bp, Wb, bb,
                                S12, Aarr, Carr);
    kQ<<<dim3(16, 16), 512, 0, stream>>>(S12, Aarr, Carr, Wb, noise,
                                         (float*)d_out);
}